// Round 6
// baseline (354.108 us; speedup 1.0000x reference)
//
#include <hip/hip_runtime.h>
#include <hip/hip_cooperative_groups.h>
#include <stdint.h>

namespace cg = cooperative_groups;

#define NBOX 8000
#define NPAD 8192
#define NW   128      // 64-bit words per mask row (stride)
#define LCAP 16       // per-row sparse list capacity (u16 entries)
#define VLIM 4224     // list path valid while V <= VLIM (V~4000 here)
#define GRID 128      // cooperative grid: 128 blocks x 256 threads

// ---- workspace layout (bytes) ----
#define COUNT_OFF 0
#define VKEYS_OFF 0x9000                     // 8192 * 8
#define U_OFF     0x20000                    // 6 unsorted arrays
#define UARR(i)   (U_OFF + (size_t)(i) * NPAD * 4)   // bx,by,bw,bh,conf,cls
#define SIDX_OFF  0x50000                    // int[8192]
#define SARR(i)   (0x58000 + (size_t)(i) * NPAD * 4) // x1,y1,x2,y2,area,cls
#define KEEP_OFF  0x98000                    // 128 * 8
#define CNT_OFF   0x99000                    // 4352 * 4 (zeroed in P0)
#define MASK_OFF  (size_t)0xA0000            // rows < V; when V<=VLIM rows<4224 => ends at LIST_OFF
#define LIST_OFF  (size_t)0x4C0000           // 4224 * 16 * 2B (only used when V<=VLIM)

__device__ __forceinline__ float sigmoidf_(float x) {
    return 1.0f / (1.0f + expf(-x));
}

__device__ __forceinline__ unsigned long long readlane64(unsigned long long v, int l) {
    unsigned int lo = (unsigned int)__builtin_amdgcn_readlane((int)(unsigned int)(v & 0xffffffffull), l);
    unsigned int hi = (unsigned int)__builtin_amdgcn_readlane((int)(unsigned int)(v >> 32), l);
    return ((unsigned long long)hi << 32) | (unsigned long long)lo;
}

__device__ __forceinline__ unsigned int get16(const ulonglong2& a, const ulonglong2& b, int t) {
    unsigned long long src;
    if (t < 8) src = (t < 4) ? a.x : a.y;
    else       src = (t < 12) ? b.x : b.y;
    return (unsigned int)((src >> ((t & 3) << 4)) & 0xFFFFull);
}

__global__ __launch_bounds__(256) void fused_kernel(const float* __restrict__ x,
                                                    const float* __restrict__ anchors,
                                                    float* __restrict__ out,
                                                    unsigned char* __restrict__ ws) {
    cg::grid_group grid = cg::this_grid();
    const int tid  = threadIdx.x;
    const int lane = tid & 63;
    const int gtid = blockIdx.x * 256 + tid;

    __shared__ unsigned long long smemU[264];   // union: P2 tile / P3 cols / P4 supp bitmap

    // ================= P0: zero count + per-row list counts =================
    if (gtid == 0) *(unsigned int*)(ws + COUNT_OFF) = 0u;
    if (gtid < 4352) ((unsigned int*)(ws + CNT_OFF))[gtid] = 0u;
    __threadfence();
    grid.sync();

    // ================= P1: decode (wave-aggregated compaction) =================
    if (gtid < NBOX) {
        int n   = gtid;                         // 8000 = 125 full waves
        int a   = n / 1600;
        int pos = n - a * 1600;
        int gy  = pos / 40;
        int gx  = pos - gy * 40;
        const float* p = x + (size_t)a * 25 * 1600 + pos;

        float tx   = sigmoidf_(p[0]);
        float ty   = sigmoidf_(p[1600]);
        float tw   = p[2 * 1600];
        float th   = p[3 * 1600];
        float conf = sigmoidf_(p[4 * 1600]);

        float best = -1.0f; int bi = 0;
        #pragma unroll
        for (int c = 0; c < 20; ++c) {          // first-max wins, matches jnp.argmax
            float v = sigmoidf_(p[(5 + c) * 1600]);
            if (v > best) { best = v; bi = c; }
        }

        float aw = anchors[a * 2 + 0];
        float ah = anchors[a * 2 + 1];
        float bx = (tx + (float)gx) * 8.0f;
        float by = (ty + (float)gy) * 8.0f;
        float bw = expf(tw) * aw * 8.0f;
        float bh = expf(th) * ah * 8.0f;

        ((float*)(ws + UARR(0)))[n] = bx;
        ((float*)(ws + UARR(1)))[n] = by;
        ((float*)(ws + UARR(2)))[n] = bw;
        ((float*)(ws + UARR(3)))[n] = bh;
        ((float*)(ws + UARR(4)))[n] = conf;
        ((float*)(ws + UARR(5)))[n] = (float)bi;

        bool valid = conf > 0.5f;               // strict >, matches ref
        unsigned long long bal = __ballot(valid);
        if (bal) {
            int lead = __builtin_ctzll(bal);
            unsigned int base = 0;
            if (lane == lead)
                base = atomicAdd((unsigned int*)(ws + COUNT_OFF), (unsigned int)__popcll(bal));
            base = (unsigned int)__shfl((int)base, lead, 64);
            if (valid) {
                unsigned int cb = __float_as_uint(conf);   // conf in (0,1): bits monotonic
                unsigned long long key = ((unsigned long long)cb << 32) | (unsigned long long)(8191 - n);
                unsigned int slot = base + (unsigned int)__popcll(bal & ((1ull << lane) - 1ull));
                ((unsigned long long*)(ws + VKEYS_OFF))[slot] = key;
            }
        }
    }
    __threadfence();
    grid.sync();

    // ================= P2: block-complete rank + scatter =================
    int V = (int)*(const unsigned int*)(ws + COUNT_OFF);
    if (V > NPAD) V = NPAD;
    {
#pragma clang fp contract(off)
        int i0 = blockIdx.x << 8;
        if (i0 < NPAD) {
            unsigned long long* tile = smemU;
            const unsigned long long* vk = (const unsigned long long*)(ws + VKEYS_OFF);
            int i = i0 + tid;
            float* sx1 = (float*)(ws + SARR(0));
            float* sy1 = (float*)(ws + SARR(1));
            float* sx2 = (float*)(ws + SARR(2));
            float* sy2 = (float*)(ws + SARR(3));
            float* sar = (float*)(ws + SARR(4));
            float* scl = (float*)(ws + SARR(5));
            if (i0 < V) {                       // block-uniform
                unsigned long long ki = (i < V) ? vk[i] : ~0ull;
                int cntr = 0;
                int ntiles = (V + 255) >> 8;
                for (int tb = 0; tb < ntiles; ++tb) {
                    int j = (tb << 8) + tid;
                    tile[tid] = (j < V) ? vk[j] : 0ull;   // pad 0 never counts (keys > 0)
                    __syncthreads();
                    int lim = V - (tb << 8);
                    if (lim >= 256) {
                        #pragma unroll 8
                        for (int jj = 0; jj < 256; ++jj) cntr += (tile[jj] > ki) ? 1 : 0;
                    } else {
                        for (int jj = 0; jj < lim; ++jj) cntr += (tile[jj] > ki) ? 1 : 0;
                    }
                    __syncthreads();
                }
                if (i < V) {                    // rank is final: scatter now
                    int r   = cntr;
                    int idx = 8191 - (int)(ki & 0x1FFFull);
                    ((int*)(ws + SIDX_OFF))[r] = idx;
                    float cx = ((float*)(ws + UARR(0)))[idx];
                    float cy = ((float*)(ws + UARR(1)))[idx];
                    float w  = ((float*)(ws + UARR(2)))[idx];
                    float h  = ((float*)(ws + UARR(3)))[idx];
                    float x1 = cx - w / 2.0f;
                    float y1 = cy - h / 2.0f;
                    float x2 = cx + w / 2.0f;
                    float y2 = cy + h / 2.0f;
                    sx1[r] = x1; sy1[r] = y1; sx2[r] = x2; sy2[r] = y2;
                    sar[r] = fabsf((x2 - x1) * (y2 - y1));   // ref: recomputed from corners
                    scl[r] = ((float*)(ws + UARR(5)))[idx];
                }
            }
            if (i >= V && i < NPAD) {           // ranks [V, NPAD): defaults
                int r = i;
                ((int*)(ws + SIDX_OFF))[r] = -1;
                sx1[r] = 0.f; sy1[r] = 0.f; sx2[r] = 0.f; sy2[r] = 0.f;
                sar[r] = 0.f; scl[r] = -1.0f;
            }
        }
    }
    __threadfence();
    grid.sync();

    // ================= P3: suppression bitmask + sparse lists =================
    {
#pragma clang fp contract(off)
        int nwords = (V + 63) >> 6;
        int nrb    = (V + 255) >> 8;
        const float* sx1 = (const float*)(ws + SARR(0));
        const float* sy1 = (const float*)(ws + SARR(1));
        const float* sx2 = (const float*)(ws + SARR(2));
        const float* sy2 = (const float*)(ws + SARR(3));
        const float* sar = (const float*)(ws + SARR(4));
        const float* scl = (const float*)(ws + SARR(5));
        float* fs  = (float*)smemU;
        float* cx1 = fs;       float* cy1 = fs + 64;  float* cx2 = fs + 128;
        float* cy2 = fs + 192; float* car = fs + 256; float* ccl = fs + 320;

        int u = 0;
        for (int rb = 0; rb < nrb; ++rb) {
            int i0 = rb << 8;
            for (int w = rb << 2; w < nwords; ++w, ++u) {   // only words with j0+64 > i0
                if ((u & (GRID - 1)) != (int)blockIdx.x) continue;  // block-uniform
                int j0 = w << 6;
                if (tid < 64) {
                    int j = j0 + tid;                        // SARR defined for all 8192
                    cx1[tid] = sx1[j]; cy1[tid] = sy1[j];
                    cx2[tid] = sx2[j]; cy2[tid] = sy2[j];
                    car[tid] = sar[j]; ccl[tid] = scl[j];
                }
                __syncthreads();
                int i = i0 + tid;
                if (i < V) {
                    unsigned long long word = 0;
                    if (j0 + 64 > i + 1) {
                        float x1i = sx1[i], y1i = sy1[i], x2i = sx2[i], y2i = sy2[i];
                        float ai = sar[i], ci = scl[i];
                        for (int jj = 0; jj < 64; ++jj) {
                            int j = j0 + jj;
                            if (j <= i || j >= V) continue;
                            if (ccl[jj] != ci) continue;
                            float iw = fminf(x2i, cx2[jj]) - fmaxf(x1i, cx1[jj]);
                            iw = fmaxf(iw, 0.0f);
                            float ih = fminf(y2i, cy2[jj]) - fmaxf(y1i, cy1[jj]);
                            ih = fmaxf(ih, 0.0f);
                            float inter = iw * ih;
                            float denom = ai + car[jj] - inter + 1e-6f;  // ((ai+aj)-inter)+eps, L-to-R
                            if (inter / denom >= 0.5f) word |= (1ull << jj);
                        }
                    }
                    ((unsigned long long*)(ws + MASK_OFF))[(size_t)i * NW + w] = word;
                    if (word && V <= VLIM) {                 // sparse list emission
                        int pc = __popcll(word);
                        unsigned int b = atomicAdd((unsigned int*)(ws + CNT_OFF) + i, (unsigned int)pc);
                        unsigned long long t = word;
                        unsigned int o = 0;
                        while (t) {
                            int bit = __builtin_ctzll(t);
                            t &= t - 1ull;
                            unsigned int slot = b + o; ++o;
                            if (slot < LCAP)
                                ((unsigned short*)(ws + LIST_OFF))[(size_t)i * LCAP + slot] =
                                    (unsigned short)(j0 + bit);
                        }
                    }
                }
                __syncthreads();                             // LDS reused next unit
            }
        }
    }
    __threadfence();
    grid.sync();

    // ================= P4: greedy scan (block 0, wave 0, zero barriers) =================
    if (blockIdx.x == 0 && tid < 64) {
        const unsigned long long* mask = (const unsigned long long*)(ws + MASK_OFF);
        const unsigned int*  cnt  = (const unsigned int*)(ws + CNT_OFF);
        const ulonglong2*    lst  = (const ulonglong2*)(ws + LIST_OFF);
        unsigned long long*  keepw = (unsigned long long*)(ws + KEEP_OFF);
        unsigned int* supp2 = (unsigned int*)smemU;          // 8192-bit suppression bitmap
        #pragma unroll
        for (int k = 0; k < 4; ++k) supp2[lane * 4 + k] = 0u;

        int nch  = (V + 63) >> 6;
        int maxw = nch;
        bool useL = (V <= VLIM);

        unsigned int cA = 0; ulonglong2 lA0 = {0,0}, lA1 = {0,0};
        if (useL && lane < V) {
            cA  = cnt[lane];
            lA0 = lst[(size_t)lane * 2];
            lA1 = lst[(size_t)lane * 2 + 1];
        }

        for (int c = 0; c < nch; ++c) {
            int base = c << 6;
            int row  = base + lane;

            unsigned int cB = 0; ulonglong2 lB0 = {0,0}, lB1 = {0,0};
            {
                int row2 = base + 64 + lane;                 // prefetch chunk c+1
                if (useL && c + 1 < nch && row2 < V) {
                    cB  = cnt[row2];
                    lB0 = lst[(size_t)row2 * 2];
                    lB1 = lst[(size_t)row2 * 2 + 1];
                }
            }

            unsigned long long aw = ((unsigned long long)supp2[2 * c + 1] << 32) | supp2[2 * c];
            int rem = V - base;
            unsigned long long tail = (rem >= 64) ? ~0ull : ((1ull << rem) - 1ull);
            unsigned long long alive = ~aw & tail;

            unsigned long long inw = 0;                      // in-chunk suppression word
            if (useL) {
                unsigned int cc = (cA < LCAP) ? cA : LCAP;
                for (int t = 0; t < LCAP; ++t) {
                    bool act = ((unsigned int)t < cc);
                    if (!__any(act)) break;
                    if (act) {
                        unsigned int j = get16(lA0, lA1, t);
                        unsigned int d = j - (unsigned int)base;
                        if (d < 64u) inw |= (1ull << d);
                    }
                }
                if (cA > LCAP && row < V) inw = mask[(size_t)row * NW + c];
            } else {
                if (row < V) inw = mask[(size_t)row * NW + c];
            }

            unsigned long long dnz = __ballot(inw != 0ull);  // greedy resolve (scalar unit)
            unsigned long long work = alive & dnz;
            while (work) {
                int k = __builtin_ctzll(work);
                work &= work - 1ull;
                unsigned long long dk = readlane64(inw, k);
                alive &= ~dk;
                work  &= ~dk;
            }

            bool am = ((alive >> lane) & 1ull) && (row < V); // scatter suppressions
            if (useL) {
                if (am && cA <= LCAP) {
                    for (unsigned int t = 0; t < cA; ++t) {
                        unsigned int j = get16(lA0, lA1, (int)t);
                        atomicOr(&supp2[j >> 5], 1u << (j & 31));
                    }
                }
                unsigned long long ofl = __ballot(am && cA > LCAP);   // rare
                while (ofl) {
                    int k = __builtin_ctzll(ofl);
                    ofl &= ofl - 1ull;
                    size_t rb2 = (size_t)(base + k) * NW;
                    for (int ww = c + lane; ww < maxw; ww += 64) {
                        unsigned long long m = mask[rb2 + ww];
                        if (m) {
                            atomicOr(&supp2[2 * ww],     (unsigned int)m);
                            atomicOr(&supp2[2 * ww + 1], (unsigned int)(m >> 32));
                        }
                    }
                }
            } else {
                unsigned long long av = __ballot(am);        // full fallback
                while (av) {
                    int k = __builtin_ctzll(av);
                    av &= av - 1ull;
                    size_t rb2 = (size_t)(base + k) * NW;
                    for (int ww = c + lane; ww < maxw; ww += 64) {
                        unsigned long long m = mask[rb2 + ww];
                        if (m) {
                            atomicOr(&supp2[2 * ww],     (unsigned int)m);
                            atomicOr(&supp2[2 * ww + 1], (unsigned int)(m >> 32));
                        }
                    }
                }
            }

            cA = cB; lA0 = lB0; lA1 = lB1;
        }

        keepw[lane]      = ~(((unsigned long long)supp2[2 * lane + 1] << 32) | supp2[2 * lane]);
        keepw[64 + lane] = ~(((unsigned long long)supp2[2 * (64 + lane) + 1] << 32) | supp2[2 * (64 + lane)]);
    }
    __threadfence();
    grid.sync();

    // ================= P5: output =================
    if (gtid < NBOX) {
        int r = gtid;
        const unsigned long long* keepw = (const unsigned long long*)(ws + KEEP_OFF);
        bool keep = (r < V) && ((keepw[r >> 6] >> (r & 63)) & 1ull);
        float o0 = 0.f, o1 = 0.f, o2 = 0.f, o3 = 0.f, o4 = 0.f, o5 = 0.f;
        if (keep) {
            int idx = ((const int*)(ws + SIDX_OFF))[r];
            if (idx >= 0 && idx < NBOX) {
                o0 = ((const float*)(ws + UARR(0)))[idx];
                o1 = ((const float*)(ws + UARR(1)))[idx];
                o2 = ((const float*)(ws + UARR(2)))[idx];
                o3 = ((const float*)(ws + UARR(3)))[idx];
                o4 = ((const float*)(ws + UARR(4)))[idx];
                o5 = ((const float*)(ws + UARR(5)))[idx];
            }
        }
        out[r * 6 + 0] = o0;
        out[r * 6 + 1] = o1;
        out[r * 6 + 2] = o2;
        out[r * 6 + 3] = o3;
        out[r * 6 + 4] = o4;
        out[r * 6 + 5] = o5;
    }
}

extern "C" void kernel_launch(void* const* d_in, const int* in_sizes, int n_in,
                              void* d_out, int out_size, void* d_ws, size_t ws_size,
                              hipStream_t stream) {
    const float* x       = (const float*)d_in[0];
    const float* anchors = (const float*)d_in[1];
    float* out           = (float*)d_out;
    unsigned char* ws    = (unsigned char*)d_ws;

    void* args[] = { (void*)&x, (void*)&anchors, (void*)&out, (void*)&ws };
    hipLaunchCooperativeKernel((void*)fused_kernel, dim3(GRID), dim3(256), args, 0, stream);
}

// Round 7
// 154.386 us; speedup vs baseline: 2.2936x; 2.2936x over previous
//
#include <hip/hip_runtime.h>
#include <stdint.h>

#define NBOX 8000
#define NPAD 8192
#define NW   128      // 64-bit words per mask row (stride)
#define LCAP 16       // per-row sparse list capacity (u16 entries)
#define VLIM 4224     // list path valid while V <= VLIM (V~4000 here)

// ---- workspace layout (bytes) ----
#define COUNT_OFF 0
#define VKEYS_OFF 0x9000                     // 8192 * 8
#define U_OFF     0x20000                    // 6 unsorted arrays
#define UARR(i)   (U_OFF + (size_t)(i) * NPAD * 4)   // bx,by,bw,bh,conf,cls
#define SIDX_OFF  0x50000                    // int[8192]
#define SARR(i)   (0x58000 + (size_t)(i) * NPAD * 4) // x1,y1,x2,y2,area,cls
#define KEEP_OFF  0x98000                    // 128 * 8
#define CNT_OFF   0x99000                    // 4352 * 4 (zeroed by rank_scatter)
#define MASK_OFF  (size_t)0xA0000            // rows < V; V<=VLIM keeps it under LIST_OFF
#define LIST_OFF  (size_t)0x4C0000           // 4224 * 16 * 2B (used when V<=VLIM)

__device__ __forceinline__ float sigmoidf_(float x) {
    return 1.0f / (1.0f + expf(-x));
}

__device__ __forceinline__ unsigned long long readlane64(unsigned long long v, int l) {
    unsigned int lo = (unsigned int)__builtin_amdgcn_readlane((int)(unsigned int)(v & 0xffffffffull), l);
    unsigned int hi = (unsigned int)__builtin_amdgcn_readlane((int)(unsigned int)(v >> 32), l);
    return ((unsigned long long)hi << 32) | (unsigned long long)lo;
}

__device__ __forceinline__ unsigned int get16(const ulonglong2& a, const ulonglong2& b, int t) {
    unsigned long long src;
    if (t < 8) src = (t < 4) ? a.x : a.y;
    else       src = (t < 12) ? b.x : b.y;
    return (unsigned int)((src >> ((t & 3) << 4)) & 0xFFFFull);
}

// build the in-chunk suppression word from a row's sparse list (cols in [base, base+64))
__device__ __forceinline__ unsigned long long build_inw(unsigned int c, const ulonglong2& l0,
                                                        const ulonglong2& l1, int base) {
    unsigned long long inw = 0;
    unsigned int cc = (c < LCAP) ? c : LCAP;
    for (int t = 0; t < LCAP; ++t) {
        bool act = ((unsigned int)t < cc);
        if (!__any(act)) break;
        if (act) {
            unsigned int j = get16(l0, l1, t);
            unsigned int d = j - (unsigned int)base;
            if (d < 64u) inw |= (1ull << d);
        }
    }
    return inw;
}

// ---------------- decode: 1 wave/block, wave-aggregated key compaction ----------------
__global__ __launch_bounds__(64) void decode_kernel(const float* __restrict__ x,
                                                    const float* __restrict__ anchors,
                                                    unsigned char* __restrict__ ws) {
    int n = blockIdx.x * 64 + threadIdx.x;          // 125*64 = 8000 exactly
    int a   = n / 1600;
    int pos = n - a * 1600;
    int gy  = pos / 40;
    int gx  = pos - gy * 40;
    const float* p = x + (size_t)a * 25 * 1600 + pos;

    float tx   = sigmoidf_(p[0]);
    float ty   = sigmoidf_(p[1600]);
    float tw   = p[2 * 1600];
    float th   = p[3 * 1600];
    float conf = sigmoidf_(p[4 * 1600]);

    float best = -1.0f; int bi = 0;
    #pragma unroll
    for (int c = 0; c < 20; ++c) {                  // first-max wins, matches jnp.argmax
        float v = sigmoidf_(p[(5 + c) * 1600]);
        if (v > best) { best = v; bi = c; }
    }

    float aw = anchors[a * 2 + 0];
    float ah = anchors[a * 2 + 1];
    float bx = (tx + (float)gx) * 8.0f;
    float by = (ty + (float)gy) * 8.0f;
    float bw = expf(tw) * aw * 8.0f;
    float bh = expf(th) * ah * 8.0f;

    ((float*)(ws + UARR(0)))[n] = bx;
    ((float*)(ws + UARR(1)))[n] = by;
    ((float*)(ws + UARR(2)))[n] = bw;
    ((float*)(ws + UARR(3)))[n] = bh;
    ((float*)(ws + UARR(4)))[n] = conf;
    ((float*)(ws + UARR(5)))[n] = (float)bi;

    bool valid = conf > 0.5f;                       // strict >, matches ref
    unsigned long long bal = __ballot(valid);
    if (bal) {
        int lead = __builtin_ctzll(bal);
        unsigned int base = 0;
        if ((int)threadIdx.x == lead)
            base = atomicAdd((unsigned int*)(ws + COUNT_OFF), (unsigned int)__popcll(bal));
        base = (unsigned int)__shfl((int)base, lead, 64);
        if (valid) {
            unsigned int cb = __float_as_uint(conf);   // conf in (0,1): bits monotonic
            unsigned long long key = ((unsigned long long)cb << 32) | (unsigned long long)(8191 - n);
            unsigned int slot = base + (unsigned int)__popcll(bal & ((1ull << threadIdx.x) - 1ull));
            ((unsigned long long*)(ws + VKEYS_OFF))[slot] = key;
        }
    }
}

// ---------------- block-complete rank + scatter (one pass, no atomics) ----------------
// Block b owns rows [b*64, b*64+64); 4 threads/row split the j-dimension over
// LDS tiles (broadcast reads). Partials summed in LDS; wave 0 scatters geometry.
// Keys unique -> ranks are a permutation == stable argsort(-conf). Also zeros CNT.
__global__ __launch_bounds__(256) void rank_scatter_kernel(unsigned char* __restrict__ ws) {
#pragma clang fp contract(off)
    __shared__ unsigned long long tile[256];
    __shared__ int partial[256];
    int V = *(const int*)(ws + COUNT_OFF);
    if (V > NPAD) V = NPAD;
    int tid  = threadIdx.x;
    int lane = tid & 63;
    int q    = tid >> 6;                            // quarter 0..3
    int b    = blockIdx.x;                          // 128 blocks
    int i    = (b << 6) + lane;                     // row owned by this lane
    int gtid = b * 256 + tid;
    if (gtid < 4352) ((unsigned int*)(ws + CNT_OFF))[gtid] = 0u;   // zero list counts

    const unsigned long long* vk = (const unsigned long long*)(ws + VKEYS_OFF);
    unsigned long long ki = (i < V) ? vk[i] : ~0ull;
    int cnt = 0;
    if ((b << 6) < V) {                             // block-uniform
        int ntiles = (V + 255) >> 8;
        for (int tb = 0; tb < ntiles; ++tb) {
            int j = (tb << 8) + tid;
            tile[tid] = (j < V) ? vk[j] : 0ull;     // pad 0 never counts (keys > 0)
            __syncthreads();
            int basej = (tb << 8) + (q << 6);
            int lim = V - basej;
            if (lim > 64) lim = 64;
            const unsigned long long* tq = &tile[q << 6];
            if (lim == 64) {
                #pragma unroll 16
                for (int jj = 0; jj < 64; ++jj) cnt += (tq[jj] > ki) ? 1 : 0;
            } else {
                for (int jj = 0; jj < lim; ++jj) cnt += (tq[jj] > ki) ? 1 : 0;
            }
            __syncthreads();
        }
    }
    partial[tid] = cnt;
    __syncthreads();
    if (q == 0) {
        float* sx1 = (float*)(ws + SARR(0));
        float* sy1 = (float*)(ws + SARR(1));
        float* sx2 = (float*)(ws + SARR(2));
        float* sy2 = (float*)(ws + SARR(3));
        float* sar = (float*)(ws + SARR(4));
        float* scl = (float*)(ws + SARR(5));
        if (i < V) {
            int r = partial[lane] + partial[64 + lane] + partial[128 + lane] + partial[192 + lane];
            int idx = 8191 - (int)(ki & 0x1FFFull);
            ((int*)(ws + SIDX_OFF))[r] = idx;
            float cx = ((float*)(ws + UARR(0)))[idx];
            float cy = ((float*)(ws + UARR(1)))[idx];
            float w  = ((float*)(ws + UARR(2)))[idx];
            float h  = ((float*)(ws + UARR(3)))[idx];
            float x1 = cx - w / 2.0f;
            float y1 = cy - h / 2.0f;
            float x2 = cx + w / 2.0f;
            float y2 = cy + h / 2.0f;
            sx1[r] = x1; sy1[r] = y1; sx2[r] = x2; sy2[r] = y2;
            sar[r] = fabsf((x2 - x1) * (y2 - y1));  // ref: recomputed from corners
            scl[r] = ((float*)(ws + UARR(5)))[idx];
        } else {                                    // rank positions [V, NPAD): defaults
            ((int*)(ws + SIDX_OFF))[i] = -1;
            sx1[i] = 0.f; sy1[i] = 0.f; sx2[i] = 0.f; sy2[i] = 0.f;
            sar[i] = 0.f; scl[i] = -1.0f;
        }
    }
}

// ---------------- suppression bitmask + sparse per-row column lists ----------------
__global__ __launch_bounds__(256) void mask_kernel(unsigned char* __restrict__ ws) {
#pragma clang fp contract(off)
    int V = *(int*)(ws + COUNT_OFF);
    if (V > NPAD) V = NPAD;
    int i0 = blockIdx.y * 256;
    int w  = blockIdx.x;
    int j0 = w * 64;
    if (i0 >= V) return;
    if (j0 >= V) return;
    if (j0 + 64 <= i0) return;                     // strictly sub-diagonal: all zero
    int i  = i0 + threadIdx.x;

    const float* sx1 = (const float*)(ws + SARR(0));
    const float* sy1 = (const float*)(ws + SARR(1));
    const float* sx2 = (const float*)(ws + SARR(2));
    const float* sy2 = (const float*)(ws + SARR(3));
    const float* sar = (const float*)(ws + SARR(4));
    const float* scl = (const float*)(ws + SARR(5));

    __shared__ float cx1[64], cy1[64], cx2[64], cy2[64], car[64], ccl[64];
    if (threadIdx.x < 64) {
        int j = j0 + threadIdx.x;
        cx1[threadIdx.x] = sx1[j]; cy1[threadIdx.x] = sy1[j];
        cx2[threadIdx.x] = sx2[j]; cy2[threadIdx.x] = sy2[j];
        car[threadIdx.x] = sar[j]; ccl[threadIdx.x] = scl[j];
    }
    __syncthreads();
    if (i >= V) return;

    unsigned long long word = 0;
    if (j0 + 64 > i + 1) {
        float x1i = sx1[i], y1i = sy1[i], x2i = sx2[i], y2i = sy2[i];
        float ai = sar[i], ci = scl[i];
        for (int jj = 0; jj < 64; ++jj) {
            int j = j0 + jj;
            if (j <= i || j >= V) continue;
            if (ccl[jj] != ci) continue;
            float iw = fminf(x2i, cx2[jj]) - fmaxf(x1i, cx1[jj]);
            iw = fmaxf(iw, 0.0f);
            float ih = fminf(y2i, cy2[jj]) - fmaxf(y1i, cy1[jj]);
            ih = fmaxf(ih, 0.0f);
            float inter = iw * ih;
            float denom = ai + car[jj] - inter + 1e-6f;   // ((ai+aj)-inter)+eps, L-to-R
            if (inter / denom >= 0.5f) word |= (1ull << jj);
        }
    }
    ((unsigned long long*)(ws + MASK_OFF))[(size_t)i * NW + w] = word;

    if (word && V <= VLIM) {                       // sparse list emission
        int pc = __popcll(word);
        unsigned int b = atomicAdd((unsigned int*)(ws + CNT_OFF) + i, (unsigned int)pc);
        unsigned long long t = word;
        unsigned int o = 0;
        while (t) {
            int bit = __builtin_ctzll(t);
            t &= t - 1ull;
            unsigned int slot = b + o; ++o;
            if (slot < LCAP)
                ((unsigned short*)(ws + LIST_OFF))[(size_t)i * LCAP + slot] =
                    (unsigned short)(j0 + bit);
        }
    }
}

// ---------------- greedy scan: ONE wave, zero barriers, pipelined inw ----------------
// supp = u64[128] in LDS (ds_or_b64 atomics, same-wave DS ordering). Per chunk:
// inw for chunk c+1 is PREBUILT during chunk c (prefetch), keeping the serial
// critical path at: LDS read supp[c] -> scalar greedy resolve -> list scatter.
__global__ __launch_bounds__(64, 1) void scan_kernel(unsigned char* __restrict__ ws) {
    int lane = threadIdx.x;
    int V = *(const int*)(ws + COUNT_OFF);
    if (V > NPAD) V = NPAD;
    const unsigned long long* mask = (const unsigned long long*)(ws + MASK_OFF);
    const unsigned int*  cnt = (const unsigned int*)(ws + CNT_OFF);
    const ulonglong2*    lst = (const ulonglong2*)(ws + LIST_OFF);
    unsigned long long*  keepw = (unsigned long long*)(ws + KEEP_OFF);

    __shared__ unsigned long long supp[128];       // 8192-bit suppression bitmap
    supp[lane] = 0ull; supp[64 + lane] = 0ull;     // same-wave DS ordering, no barrier

    int nch  = (V + 63) >> 6;
    int maxw = nch;
    bool useL = (V <= VLIM);

    unsigned int cA = 0; ulonglong2 lA0 = {0,0}, lA1 = {0,0};
    unsigned long long inwA = 0;
    if (nch > 0 && lane < V) {                     // chunk 0 lists + inw
        if (useL) { cA = cnt[lane]; lA0 = lst[(size_t)lane * 2]; lA1 = lst[(size_t)lane * 2 + 1]; }
        if (!useL || cA > LCAP) inwA = mask[(size_t)lane * NW];
        else                    inwA = build_inw(cA, lA0, lA1, 0);
    }

    for (int c = 0; c < nch; ++c) {
        int base = c << 6;
        int row  = base + lane;

        // prefetch + prebuild chunk c+1 (independent of this chunk's resolve)
        unsigned int cB = 0; ulonglong2 lB0 = {0,0}, lB1 = {0,0};
        unsigned long long inwB = 0;
        if (c + 1 < nch) {
            int row2 = base + 64 + lane;
            if (row2 < V) {
                if (useL) { cB = cnt[row2]; lB0 = lst[(size_t)row2 * 2]; lB1 = lst[(size_t)row2 * 2 + 1]; }
                if (!useL || cB > LCAP) inwB = mask[(size_t)row2 * NW + (c + 1)];
                else                    inwB = build_inw(cB, lB0, lB1, base + 64);
            }
        }

        unsigned long long aw = supp[c];           // broadcast LDS read
        int rem = V - base;
        unsigned long long tail = (rem >= 64) ? ~0ull : ((1ull << rem) - 1ull);
        unsigned long long alive = ~aw & tail;

        unsigned long long dnz = __ballot(inwA != 0ull);   // greedy resolve (scalar unit)
        unsigned long long work = alive & dnz;
        while (work) {
            int k = __builtin_ctzll(work);
            work &= work - 1ull;
            unsigned long long dk = readlane64(inwA, k);
            alive &= ~dk;
            work  &= ~dk;
        }

        bool am = ((alive >> lane) & 1ull) && (row < V);   // scatter suppressions
        if (useL) {
            if (am && cA <= LCAP) {
                for (unsigned int t = 0; t < cA; ++t) {
                    unsigned int j = get16(lA0, lA1, (int)t);
                    atomicOr(&supp[j >> 6], 1ull << (j & 63));
                }
            }
            unsigned long long ofl = __ballot(am && cA > LCAP);    // rare overflow rows
            while (ofl) {
                int k = __builtin_ctzll(ofl);
                ofl &= ofl - 1ull;
                size_t rb = (size_t)(base + k) * NW;
                for (int ww = c + lane; ww < maxw; ww += 64) {
                    unsigned long long m = mask[rb + ww];
                    if (m) atomicOr(&supp[ww], m);
                }
            }
        } else {
            unsigned long long av = __ballot(am);                  // full fallback
            while (av) {
                int k = __builtin_ctzll(av);
                av &= av - 1ull;
                size_t rb = (size_t)(base + k) * NW;
                for (int ww = c + lane; ww < maxw; ww += 64) {
                    unsigned long long m = mask[rb + ww];
                    if (m) atomicOr(&supp[ww], m);
                }
            }
        }

        cA = cB; lA0 = lB0; lA1 = lB1; inwA = inwB;
    }

    keepw[lane]      = ~supp[lane];
    keepw[64 + lane] = ~supp[64 + lane];
}

// ---------------- write output ----------------
__global__ __launch_bounds__(256) void output_kernel(const unsigned char* __restrict__ ws,
                                                     float* __restrict__ out) {
    int r = blockIdx.x * 256 + threadIdx.x;
    if (r >= NBOX) return;
    int V = *(const int*)(ws + COUNT_OFF);
    if (V > NPAD) V = NPAD;
    const unsigned long long* keepw = (const unsigned long long*)(ws + KEEP_OFF);
    bool keep = (r < V) && ((keepw[r >> 6] >> (r & 63)) & 1ull);
    float o0 = 0.f, o1 = 0.f, o2 = 0.f, o3 = 0.f, o4 = 0.f, o5 = 0.f;
    if (keep) {
        int idx = ((const int*)(ws + SIDX_OFF))[r];
        if (idx >= 0 && idx < NBOX) {
            o0 = ((const float*)(ws + UARR(0)))[idx];
            o1 = ((const float*)(ws + UARR(1)))[idx];
            o2 = ((const float*)(ws + UARR(2)))[idx];
            o3 = ((const float*)(ws + UARR(3)))[idx];
            o4 = ((const float*)(ws + UARR(4)))[idx];
            o5 = ((const float*)(ws + UARR(5)))[idx];
        }
    }
    out[r * 6 + 0] = o0;
    out[r * 6 + 1] = o1;
    out[r * 6 + 2] = o2;
    out[r * 6 + 3] = o3;
    out[r * 6 + 4] = o4;
    out[r * 6 + 5] = o5;
}

extern "C" void kernel_launch(void* const* d_in, const int* in_sizes, int n_in,
                              void* d_out, int out_size, void* d_ws, size_t ws_size,
                              hipStream_t stream) {
    const float* x       = (const float*)d_in[0];
    const float* anchors = (const float*)d_in[1];
    float* out           = (float*)d_out;
    unsigned char* ws    = (unsigned char*)d_ws;

    hipMemsetAsync(ws + COUNT_OFF, 0, 4, stream);          // zero valid-count only
    decode_kernel<<<125, 64, 0, stream>>>(x, anchors, ws);
    rank_scatter_kernel<<<NPAD / 64, 256, 0, stream>>>(ws);
    dim3 mgrid(NW, NPAD / 256);
    mask_kernel<<<mgrid, 256, 0, stream>>>(ws);
    scan_kernel<<<1, 64, 0, stream>>>(ws);
    output_kernel<<<(NBOX + 255) / 256, 256, 0, stream>>>(ws, out);
}